// Round 1
// baseline (341.977 us; speedup 1.0000x reference)
//
#include <hip/hip_runtime.h>
#include <math.h>

// Problem constants (from setup_inputs): C=256, H=W=128, PH=PW=8, N from in_sizes.
#define C_ 256
#define H_ 128
#define W_ 128
#define PH_ 8
#define PW_ 8

// One wave (64 lanes) handles one (n, c) pair.
// Block = 256 threads = 4 waves; grid = ((N+3)/4, C).
__global__ __launch_bounds__(256) void roi_pool_kernel(
    const float* __restrict__ fm,
    const int* __restrict__ rois,
    float* __restrict__ out,
    int N)
{
    const int wid  = threadIdx.x >> 6;
    const int lane = threadIdx.x & 63;
    const int n    = blockIdx.x * 4 + wid;   // wave-uniform
    const int c    = blockIdx.y;
    if (n >= N) return;

    // roi = (y, x, rH, rW), int32, 16B-aligned
    const int4 roi = ((const int4*)rois)[n];
    const int y  = roi.x;
    const int x  = roi.y;
    const int rH = roi.z;
    const int rW = roi.w;

    const float* plane = fm + (size_t)c * (H_ * W_) + x;

    const bool wide = (rW > 64);           // wave-uniform
    const bool v1   = (lane + 64) < rW;    // second-column-set validity

    #pragma unroll
    for (int ph = 0; ph < PH_; ++ph) {
        // h-bin = [floor(ph*rH/8), ceil((ph+1)*rH/8))  (union of idA/idB segments)
        const int hs = (ph * rH) >> 3;
        const int he = ((ph + 1) * rH + 7) >> 3;

        const float* p = plane + (size_t)(y + hs) * W_;
        float m0 = -INFINITY;   // running max for column w = lane
        float m1 = -INFINITY;   // running max for column w = lane + 64

        if (wide) {
            for (int h = hs; h < he; ++h, p += W_) {
                m0 = fmaxf(m0, p[lane]);          // lane < 64 <= rW: always valid
                if (v1) m1 = fmaxf(m1, p[lane + 64]);
            }
        } else {
            const bool v0 = lane < rW;
            for (int h = hs; h < he; ++h, p += W_) {
                if (v0) m0 = fmaxf(m0, p[lane]);
            }
        }

        // w-pooling: 8 lanes per pw-bin gather columns via shuffle.
        // bin pw covers [floor(pw*rW/8), ceil((pw+1)*rW/8)); span <= 18 <= 24 covered.
        const int pw = lane & 7;
        const int j  = lane >> 3;
        const int ws = (pw * rW) >> 3;
        const int we = ((pw + 1) * rW + 7) >> 3;

        float r = -INFINITY;
        #pragma unroll
        for (int k = 0; k < 3; ++k) {
            const int w = ws + j + k * 8;
            // shuffles must be unconditional (all lanes active)
            const float a = __shfl(m0, w & 63, 64);
            const float b = __shfl(m1, w & 63, 64);
            if (w < we) r = fmaxf(r, (w < 64) ? a : b);
        }
        // reduce the 8 partials per bin (lanes pw, pw+8, ..., pw+56)
        r = fmaxf(r, __shfl_xor(r, 8, 64));
        r = fmaxf(r, __shfl_xor(r, 16, 64));
        r = fmaxf(r, __shfl_xor(r, 32, 64));

        if (lane < PW_) {
            out[(((size_t)n * C_ + c) * PH_ + ph) * PW_ + lane] = r;
        }
    }
}

extern "C" void kernel_launch(void* const* d_in, const int* in_sizes, int n_in,
                              void* d_out, int out_size, void* d_ws, size_t ws_size,
                              hipStream_t stream) {
    const float* fm   = (const float*)d_in[0];
    const int*   rois = (const int*)d_in[1];
    float*       out  = (float*)d_out;
    const int N = in_sizes[1] / 4;

    dim3 grid((N + 3) / 4, C_);
    roi_pool_kernel<<<grid, 256, 0, stream>>>(fm, rois, out, N);
}

// Round 2
// 215.961 us; speedup vs baseline: 1.5835x; 1.5835x over previous
//
#include <hip/hip_runtime.h>
#include <math.h>

// Problem constants: C=256, H=W=128, PH=PW=8.
#define C_ 256
#define H_ 128
#define W_ 128
#define PH_ 8
#define PW_ 8

// One wave per (n, c). Block = 4 waves = one ROI n, 4 consecutive channels.
// Grid: flat 64*N blocks. blockIdx%8 selects the XCD -> 32-channel chunk,
// so each XCD's L2 only holds 32 planes (2 MB) of the feature map.
__global__ __launch_bounds__(256) void roi_pool_kernel(
    const float* __restrict__ fm,
    const int* __restrict__ rois,
    float* __restrict__ out,
    int N)
{
    const int wid  = threadIdx.x >> 6;
    const int lane = threadIdx.x & 63;

    const int bid  = blockIdx.x;
    const int xcd  = bid & 7;        // heuristic: round-robin block->XCD
    const int t    = bid >> 3;
    const int csub = t & 7;
    const int n    = t >> 3;
    if (n >= N) return;
    const int c = (xcd << 5) + (csub << 2) + wid;   // xcd*32 + csub*4 + wid

    const int4 roi = ((const int4*)rois)[n];
    const int y  = roi.x;
    const int x  = roi.y;
    const int rH = roi.z;
    const int rW = roi.w;

    // Full-row float2 view: row = 128 floats = 64 float2, 512B-aligned.
    const float2* plane2 = (const float2*)(fm + (size_t)c * (H_ * W_));

    const int pw = lane & 7;
    const int j  = lane >> 3;
    const int ws = (pw * rW) >> 3;                 // floor(pw*rW/8)
    const int we = (((pw + 1) * rW) + 7) >> 3;     // ceil((pw+1)*rW/8)

    #pragma unroll
    for (int ph = 0; ph < PH_; ++ph) {
        const int hs = (ph * rH) >> 3;
        const int he = ((ph + 1) * rH + 7) >> 3;

        // lane owns absolute columns 2*lane (m0) and 2*lane+1 (m1);
        // no masking needed: the w-pool only gathers columns inside the ROI.
        const float2* p = plane2 + (size_t)(y + hs) * (W_ / 2) + lane;
        float m0 = -INFINITY, m1 = -INFINITY;

        int cnt = he - hs;
        while (cnt >= 2) {
            const float2 a = p[0];
            const float2 b = p[W_ / 2];
            p += W_;               // two rows of float2
            cnt -= 2;
            m0 = fmaxf(m0, fmaxf(a.x, b.x));
            m1 = fmaxf(m1, fmaxf(a.y, b.y));
        }
        if (cnt) {
            const float2 a = p[0];
            m0 = fmaxf(m0, a.x);
            m1 = fmaxf(m1, a.y);
        }

        // w-pool: 8 lanes per pw bin gather absolute columns x+w via shuffle.
        float r = -INFINITY;
        #pragma unroll
        for (int k = 0; k < 3; ++k) {
            const int w  = ws + j + k * 8;
            const int wa = x + w;                  // absolute column
            const float a = __shfl(m0, (wa >> 1) & 63, 64);
            const float b = __shfl(m1, (wa >> 1) & 63, 64);
            if (w < we) r = fmaxf(r, (wa & 1) ? b : a);
        }
        r = fmaxf(r, __shfl_xor(r, 8, 64));
        r = fmaxf(r, __shfl_xor(r, 16, 64));
        r = fmaxf(r, __shfl_xor(r, 32, 64));

        if (lane < PW_) {
            out[(((size_t)n * C_ + c) * PH_ + ph) * PW_ + lane] = r;
        }
    }
}

extern "C" void kernel_launch(void* const* d_in, const int* in_sizes, int n_in,
                              void* d_out, int out_size, void* d_ws, size_t ws_size,
                              hipStream_t stream) {
    const float* fm   = (const float*)d_in[0];
    const int*   rois = (const int*)d_in[1];
    float*       out  = (float*)d_out;
    const int N = in_sizes[1] / 4;

    dim3 grid(64 * N);   // 8 xcd * 8 csub * N
    roi_pool_kernel<<<grid, 256, 0, stream>>>(fm, rois, out, N);
}

// Round 3
// 154.167 us; speedup vs baseline: 2.2182x; 1.4008x over previous
//
#include <hip/hip_runtime.h>
#include <math.h>

// Problem constants: C=256, H=W=128, PH=PW=8.
#define C_ 256
#define H_ 128
#define W_ 128
#define PH_ 8
#define PW_ 8
#define HW_ (H_ * W_)

// ---------- Kernel 1: transpose (C, H*W) -> (H*W, C) ----------
// 64x64 tiles via padded LDS; reads and writes both coalesced.
__global__ __launch_bounds__(256) void transpose_kernel(
    const float* __restrict__ fm, float* __restrict__ fmt)
{
    __shared__ float tile[64][65];
    const int tx  = threadIdx.x & 63;
    const int ty  = threadIdx.x >> 6;      // 0..3
    const int hw0 = blockIdx.x * 64;
    const int c0  = blockIdx.y * 64;
    #pragma unroll
    for (int k = 0; k < 16; ++k) {
        const int c = ty + 4 * k;
        tile[c][tx] = fm[(size_t)(c0 + c) * HW_ + hw0 + tx];
    }
    __syncthreads();
    #pragma unroll
    for (int k = 0; k < 16; ++k) {
        const int r = ty + 4 * k;
        fmt[(size_t)(hw0 + r) * C_ + c0 + tx] = tile[tx][r];
    }
}

// ---------- Kernel 2: pooling from channel-major layout ----------
// Wave = (n, ph, pw, cg). cg = 32-channel group = blockIdx&7 -> XCD-local
// 2MB slice of fmt. Lane: pg = lane>>3 (position group), cl = lane&7
// (channel quad, float4). One 1KB coalesced dwordx4 load per iteration.
__global__ __launch_bounds__(256) void pool_kernel(
    const float* __restrict__ fmt, const int* __restrict__ rois,
    float* __restrict__ out, int N)
{
    const int bid  = blockIdx.x;
    const int cg   = bid & 7;            // XCD-affine channel group
    const int m    = bid >> 3;
    const int pq   = m & 1;              // pw quad
    const int ph   = (m >> 1) & 7;
    const int n    = m >> 4;

    const int wid  = threadIdx.x >> 6;
    const int lane = threadIdx.x & 63;
    const int pw   = pq * 4 + wid;       // wave-uniform
    const int pg   = lane >> 3;          // position group 0..7
    const int c    = (cg << 5) + ((lane & 7) << 2);  // channel (float4 base)

    const int4 roi = ((const int4*)rois)[n];
    const int y = roi.x, x = roi.y, rH = roi.z, rW = roi.w;

    // bin = [floor(p*L/8), ceil((p+1)*L/8))
    const int hs = (ph * rH) >> 3;
    const int he = ((ph + 1) * rH + 7) >> 3;
    const int ws = (pw * rW) >> 3;
    const int we = ((pw + 1) * rW + 7) >> 3;
    const int bw = we - ws;

    // w-steps: nfull full 8-wide steps, then one (possibly overlapping) last
    // step; overlap / clamping re-reads in-bin columns, harmless for max.
    const int nfull = (bw - 1) >> 3;
    const int wlast = (bw >= 8) ? (we - 8 + pg)
                                : (ws + min(pg, bw - 1));

    const float* rowbase = fmt + ((size_t)(y + hs) * W_ + x) * C_ + c;
    const size_t wstep = (size_t)8 * C_;

    float4 acc = make_float4(-INFINITY, -INFINITY, -INFINITY, -INFINITY);

    for (int h = hs; h < he; ++h) {
        const float* p = rowbase + (size_t)(ws + pg) * C_;
        for (int i = 0; i < nfull; ++i) {
            const float4 v = *(const float4*)p;
            p += wstep;
            acc.x = fmaxf(acc.x, v.x);
            acc.y = fmaxf(acc.y, v.y);
            acc.z = fmaxf(acc.z, v.z);
            acc.w = fmaxf(acc.w, v.w);
        }
        {
            const float4 v = *(const float4*)(rowbase + (size_t)wlast * C_);
            acc.x = fmaxf(acc.x, v.x);
            acc.y = fmaxf(acc.y, v.y);
            acc.z = fmaxf(acc.z, v.z);
            acc.w = fmaxf(acc.w, v.w);
        }
        rowbase += (size_t)W_ * C_;
    }

    // reduce across the 8 position groups (fixed xor swizzles, conflict-free)
    #pragma unroll
    for (int mask = 8; mask <= 32; mask <<= 1) {
        acc.x = fmaxf(acc.x, __shfl_xor(acc.x, mask, 64));
        acc.y = fmaxf(acc.y, __shfl_xor(acc.y, mask, 64));
        acc.z = fmaxf(acc.z, __shfl_xor(acc.z, mask, 64));
        acc.w = fmaxf(acc.w, __shfl_xor(acc.w, mask, 64));
    }

    if (lane < 8) {
        float* o = out + ((size_t)(n * C_ + c) * PH_ + ph) * PW_ + pw;
        o[0]                 = acc.x;   // channel c     (stride 64 floats per c)
        o[PH_ * PW_]         = acc.y;   // channel c+1
        o[2 * PH_ * PW_]     = acc.z;   // channel c+2
        o[3 * PH_ * PW_]     = acc.w;   // channel c+3
    }
}

// ---------- Fallback (R1 kernel) if ws is too small for the transpose ----------
__global__ __launch_bounds__(256) void roi_pool_fallback(
    const float* __restrict__ fm, const int* __restrict__ rois,
    float* __restrict__ out, int N)
{
    const int wid  = threadIdx.x >> 6;
    const int lane = threadIdx.x & 63;
    const int bid  = blockIdx.x;
    const int xcd  = bid & 7;
    const int t    = bid >> 3;
    const int csub = t & 7;
    const int n    = t >> 3;
    if (n >= N) return;
    const int c = (xcd << 5) + (csub << 2) + wid;

    const int4 roi = ((const int4*)rois)[n];
    const int y = roi.x, x = roi.y, rH = roi.z, rW = roi.w;

    const float2* plane2 = (const float2*)(fm + (size_t)c * (H_ * W_));
    const int pw = lane & 7;
    const int j  = lane >> 3;
    const int ws = (pw * rW) >> 3;
    const int we = (((pw + 1) * rW) + 7) >> 3;

    #pragma unroll
    for (int ph = 0; ph < PH_; ++ph) {
        const int hs = (ph * rH) >> 3;
        const int he = ((ph + 1) * rH + 7) >> 3;
        const float2* p = plane2 + (size_t)(y + hs) * (W_ / 2) + lane;
        float m0 = -INFINITY, m1 = -INFINITY;
        int cnt = he - hs;
        while (cnt >= 2) {
            const float2 a = p[0];
            const float2 b = p[W_ / 2];
            p += W_; cnt -= 2;
            m0 = fmaxf(m0, fmaxf(a.x, b.x));
            m1 = fmaxf(m1, fmaxf(a.y, b.y));
        }
        if (cnt) { const float2 a = p[0]; m0 = fmaxf(m0, a.x); m1 = fmaxf(m1, a.y); }

        float r = -INFINITY;
        #pragma unroll
        for (int k = 0; k < 3; ++k) {
            const int w  = ws + j + k * 8;
            const int wa = x + w;
            const float a = __shfl(m0, (wa >> 1) & 63, 64);
            const float b = __shfl(m1, (wa >> 1) & 63, 64);
            if (w < we) r = fmaxf(r, (wa & 1) ? b : a);
        }
        r = fmaxf(r, __shfl_xor(r, 8, 64));
        r = fmaxf(r, __shfl_xor(r, 16, 64));
        r = fmaxf(r, __shfl_xor(r, 32, 64));
        if (lane < PW_) out[(((size_t)n * C_ + c) * PH_ + ph) * PW_ + lane] = r;
    }
}

extern "C" void kernel_launch(void* const* d_in, const int* in_sizes, int n_in,
                              void* d_out, int out_size, void* d_ws, size_t ws_size,
                              hipStream_t stream) {
    const float* fm   = (const float*)d_in[0];
    const int*   rois = (const int*)d_in[1];
    float*       out  = (float*)d_out;
    const int N = in_sizes[1] / 4;

    const size_t need = (size_t)HW_ * C_ * sizeof(float);
    if (ws_size >= need) {
        float* fmt = (float*)d_ws;
        transpose_kernel<<<dim3(HW_ / 64, C_ / 64), 256, 0, stream>>>(fm, fmt);
        pool_kernel<<<dim3(N * 16 * 8), 256, 0, stream>>>(fmt, rois, out, N);
    } else {
        roi_pool_fallback<<<dim3(64 * N), 256, 0, stream>>>(fm, rois, out, N);
    }
}